// Round 3
// baseline (26.623 us; speedup 1.0000x reference)
//
#include <hip/hip_runtime.h>
#include <hip/hip_bf16.h>
#include <cmath>

// RoiPoolingConv: per-ROI crop + legacy-TF bilinear resize.
// img [1,H,W,C] f32, rois [1,R,4] i32 (x,y,w,h), out [1,R,P,P,C] f32.
//
// R2: sort (roi,i) row-blocks by source image row y0 (device counting sort),
// then dispatch sorted chunks per-XCD (blockIdx%8 -> XCD round robin) so
// blocks sharing image rows hit the same XCD's L2. Main kernel: one block per
// (roi,i) row, P waves, wave j owns pixel (i,j), lane owns 8 channels.

__global__ __launch_bounds__(256) void roi_sort_kernel(
    const int* __restrict__ rois, int* __restrict__ perm, int R, int P, int H) {
  __shared__ int bins[256];
  __shared__ int offs[256];
  const int tid = threadIdx.x;
  bins[tid] = 0;
  __syncthreads();
  const int N = R * P;
  const float Pf = (float)P;
  for (int idx = tid; idx < N; idx += 256) {
    const int r = idx / P;
    const int i = idx - r * P;
    const int y = rois[r * 4 + 1];
    const int h = rois[r * 4 + 3];
    const float sy = (float)y + (float)i * ((float)h / Pf);
    int key = (int)floorf(sy);
    key = min(max(key, 0), 255);
    atomicAdd(&bins[key], 1);
  }
  __syncthreads();
  if (tid < 64) {
    int s0 = 0;
#pragma unroll
    for (int k = 0; k < 4; ++k) s0 += bins[tid * 4 + k];
    int ex = s0;
#pragma unroll
    for (int d = 1; d < 64; d <<= 1) {
      int t = __shfl_up(ex, d);
      if ((tid & 63) >= d) ex += t;
    }
    ex -= s0;  // exclusive scan of 4-bin groups
    int acc = ex;
#pragma unroll
    for (int k = 0; k < 4; ++k) {
      offs[tid * 4 + k] = acc;
      acc += bins[tid * 4 + k];
    }
  }
  __syncthreads();
  for (int idx = tid; idx < N; idx += 256) {
    const int r = idx / P;
    const int i = idx - r * P;
    const int y = rois[r * 4 + 1];
    const int h = rois[r * 4 + 3];
    const float sy = (float)y + (float)i * ((float)h / Pf);
    int key = (int)floorf(sy);
    key = min(max(key, 0), 255);
    const int pos = atomicAdd(&offs[key], 1);
    perm[pos] = idx;
  }
}

__global__ __launch_bounds__(448) void roi_pool_kernel(
    const float* __restrict__ img, const int* __restrict__ rois,
    const int* __restrict__ perm,
    float* __restrict__ out, int P, int H, int W, int C, int nblk) {
  // XCD-chunked bijective swizzle (m204): sorted position s for this block.
  const int q = nblk >> 3;
  const int rr = nblk & 7;
  const int xcd = blockIdx.x & 7;
  const int base = (xcd < rr) ? xcd * (q + 1) : rr * (q + 1) + (xcd - rr) * q;
  const int s = base + (blockIdx.x >> 3);

  const int item = perm[s];          // r*P + i, sorted by source row
  const int r = item / P;
  const int i = item - r * P;
  const int j = threadIdx.x >> 6;    // wave index = output column
  const int lane = threadIdx.x & 63;

  const int x = rois[r * 4 + 0];
  const int y = rois[r * 4 + 1];
  const int w = rois[r * 4 + 2];
  const int h = rois[r * 4 + 3];

  const float Pf = (float)P;
  // Match reference fp32 semantics exactly:
  const float sy = (float)y + (float)i * ((float)h / Pf);
  const float sx = (float)x + (float)j * ((float)w / Pf);
  const float fy = floorf(sy);
  const float fx = floorf(sx);
  int y0 = (int)fy;
  int x0 = (int)fx;
  int y1 = min(y0 + 1, y + h - 1);   // from UNclipped y0
  int x1 = min(x0 + 1, x + w - 1);
  y0 = min(max(y0, 0), H - 1);
  y1 = min(max(y1, 0), H - 1);
  x0 = min(max(x0, 0), W - 1);
  x1 = min(max(x1, 0), W - 1);
  const float wy = sy - fy;          // from UNclipped floor
  const float wx = sx - fx;
  const float omwx = 1.0f - wx;
  const float omwy = 1.0f - wy;

  const float* __restrict__ p00 = img + ((size_t)y0 * W + x0) * C;
  const float* __restrict__ p01 = img + ((size_t)y0 * W + x1) * C;
  const float* __restrict__ p10 = img + ((size_t)y1 * W + x0) * C;
  const float* __restrict__ p11 = img + ((size_t)y1 * W + x1) * C;
  float* __restrict__ po = out + ((size_t)item * P + j) * C;

  // lane covers channels [lane*8, lane*8+8): two float4 per source pixel.
  for (int c = lane * 8; c < C; c += 64 * 8) {
    const float4 a00 = *reinterpret_cast<const float4*>(p00 + c);
    const float4 b00 = *reinterpret_cast<const float4*>(p00 + c + 4);
    const float4 a01 = *reinterpret_cast<const float4*>(p01 + c);
    const float4 b01 = *reinterpret_cast<const float4*>(p01 + c + 4);
    const float4 a10 = *reinterpret_cast<const float4*>(p10 + c);
    const float4 b10 = *reinterpret_cast<const float4*>(p10 + c + 4);
    const float4 a11 = *reinterpret_cast<const float4*>(p11 + c);
    const float4 b11 = *reinterpret_cast<const float4*>(p11 + c + 4);

    float4 oa, ob;
#define LERP(DST, F, v00_, v01_, v10_, v11_)                  \
    {                                                          \
      const float top = v00_.F * omwx + v01_.F * wx;           \
      const float bot = v10_.F * omwx + v11_.F * wx;           \
      DST.F = top * omwy + bot * wy;                           \
    }
    LERP(oa, x, a00, a01, a10, a11)
    LERP(oa, y, a00, a01, a10, a11)
    LERP(oa, z, a00, a01, a10, a11)
    LERP(oa, w, a00, a01, a10, a11)
    LERP(ob, x, b00, b01, b10, b11)
    LERP(ob, y, b00, b01, b10, b11)
    LERP(ob, z, b00, b01, b10, b11)
    LERP(ob, w, b00, b01, b10, b11)
#undef LERP
    *reinterpret_cast<float4*>(po + c) = oa;
    *reinterpret_cast<float4*>(po + c + 4) = ob;
  }
}

extern "C" void kernel_launch(void* const* d_in, const int* in_sizes, int n_in,
                              void* d_out, int out_size, void* d_ws, size_t ws_size,
                              hipStream_t stream) {
  const float* img = (const float*)d_in[0];
  const int* rois = (const int*)d_in[1];
  float* out = (float*)d_out;
  int* perm = (int*)d_ws;

  const int H = 200, W = 200, C = 512;
  const int R = in_sizes[1] / 4;                    // 300
  const int pp = out_size / (R * C);                // P*P = 49
  int P = 1;
  while ((P + 1) * (P + 1) <= pp) ++P;              // isqrt -> 7

  const int nblk = R * P;                           // 2100 (r,i) rows
  roi_sort_kernel<<<1, 256, 0, stream>>>(rois, perm, R, P, H);
  roi_pool_kernel<<<nblk, P * 64, 0, stream>>>(img, rois, perm, out, P, H, W, C, nblk);
}

// Round 4
// 22.157 us; speedup vs baseline: 1.2015x; 1.2015x over previous
//
#include <hip/hip_runtime.h>
#include <hip/hip_bf16.h>
#include <cmath>

// RoiPoolingConv: per-ROI crop + legacy-TF bilinear resize.
// img [1,H,W,C] f32, rois [1,R,4] i32 (x,y,w,h), out [1,R,P,P,C] f32.
//
// R3: skip exactly-zero-weight gathers. wx==0 (j==0 or P|w) makes the x1
// column's contribution bit-exactly zero -> don't load it. Same for wy==0
// and the bottom row. Clamped-duplicate coords (x1==x0 / y1==y0) reuse
// registers instead of re-loading. ~24% fewer logical read bytes.
// One wave per output pixel, 4 waves / 256-thread block, single kernel.

__global__ __launch_bounds__(256) void roi_pool_kernel(
    const float* __restrict__ img, const int* __restrict__ rois,
    float* __restrict__ out, int P, int H, int W, int C, int npix) {
  const int g = blockIdx.x * 4 + (threadIdx.x >> 6);  // global output pixel
  if (g >= npix) return;
  const int lane = threadIdx.x & 63;
  const int pp = P * P;
  const int r = g / pp;
  const int ij = g - r * pp;
  const int i = ij / P;
  const int j = ij - i * P;

  const int4 roi = *reinterpret_cast<const int4*>(rois + r * 4);
  const int x = roi.x, y = roi.y, wd = roi.z, ht = roi.w;

  const float Pf = (float)P;
  // Match reference fp32 semantics exactly:
  const float sy = (float)y + (float)i * ((float)ht / Pf);
  const float sx = (float)x + (float)j * ((float)wd / Pf);
  const float fy = floorf(sy);
  const float fx = floorf(sx);
  int y0 = (int)fy;
  int x0 = (int)fx;
  int y1 = min(y0 + 1, y + ht - 1);   // from UNclipped y0
  int x1 = min(x0 + 1, x + wd - 1);
  y0 = min(max(y0, 0), H - 1);
  y1 = min(max(y1, 0), H - 1);
  x0 = min(max(x0, 0), W - 1);
  x1 = min(max(x1, 0), W - 1);
  const float wy = sy - fy;           // from UNclipped floor
  const float wx = sx - fx;
  const float omwx = 1.0f - wx;
  const float omwy = 1.0f - wy;
  const bool xnz = (wx != 0.0f);      // wave-uniform
  const bool ynz = (wy != 0.0f);

  const float* __restrict__ p00 = img + ((size_t)y0 * W + x0) * C;
  const float* __restrict__ p01 = img + ((size_t)y0 * W + x1) * C;
  const float* __restrict__ p10 = img + ((size_t)y1 * W + x0) * C;
  const float* __restrict__ p11 = img + ((size_t)y1 * W + x1) * C;
  float* __restrict__ po = out + (size_t)g * C;

#define LERP4(dst, lo, hi, wlo, whi)          \
  dst.x = lo.x * wlo + hi.x * whi;            \
  dst.y = lo.y * wlo + hi.y * whi;            \
  dst.z = lo.z * wlo + hi.z * whi;            \
  dst.w = lo.w * wlo + hi.w * whi;

  // lane covers channels [lane*8, lane*8+8): two float4 per source pixel.
  for (int c = lane * 8; c < C; c += 64 * 8) {
    const float4 a00 = *reinterpret_cast<const float4*>(p00 + c);
    const float4 b00 = *reinterpret_cast<const float4*>(p00 + c + 4);

    float4 a01, b01;                  // only meaningful when xnz
    float4 ta, tb;                    // top-row lerp
    if (xnz) {
      if (x1 != x0) {
        a01 = *reinterpret_cast<const float4*>(p01 + c);
        b01 = *reinterpret_cast<const float4*>(p01 + c + 4);
      } else {
        a01 = a00; b01 = b00;
      }
      LERP4(ta, a00, a01, omwx, wx)
      LERP4(tb, b00, b01, omwx, wx)
    } else {
      ta = a00; tb = b00;             // v00*1 + v01*0 == v00 exactly
    }

    float4 oa, ob;
    if (ynz) {
      float4 a10, b10;
      if (y1 != y0) {
        a10 = *reinterpret_cast<const float4*>(p10 + c);
        b10 = *reinterpret_cast<const float4*>(p10 + c + 4);
      } else {
        a10 = a00; b10 = b00;
      }
      float4 ba, bb;                  // bottom-row lerp
      if (xnz) {
        float4 a11, b11;
        if (x1 != x0) {
          if (y1 != y0) {
            a11 = *reinterpret_cast<const float4*>(p11 + c);
            b11 = *reinterpret_cast<const float4*>(p11 + c + 4);
          } else {
            a11 = a01; b11 = b01;
          }
        } else {
          a11 = a10; b11 = b10;
        }
        LERP4(ba, a10, a11, omwx, wx)
        LERP4(bb, b10, b11, omwx, wx)
      } else {
        ba = a10; bb = b10;
      }
      LERP4(oa, ta, ba, omwy, wy)
      LERP4(ob, tb, bb, omwy, wy)
    } else {
      oa = ta; ob = tb;               // top*1 + bot*0 == top exactly
    }

    *reinterpret_cast<float4*>(po + c) = oa;
    *reinterpret_cast<float4*>(po + c + 4) = ob;
  }
#undef LERP4
}

extern "C" void kernel_launch(void* const* d_in, const int* in_sizes, int n_in,
                              void* d_out, int out_size, void* d_ws, size_t ws_size,
                              hipStream_t stream) {
  const float* img = (const float*)d_in[0];
  const int* rois = (const int*)d_in[1];
  float* out = (float*)d_out;

  const int H = 200, W = 200, C = 512;
  const int R = in_sizes[1] / 4;                    // 300
  const int pp = out_size / (R * C);                // P*P = 49
  int P = 1;
  while ((P + 1) * (P + 1) <= pp) ++P;              // isqrt -> 7

  const int npix = R * pp;                          // 14,700 output pixels
  const int blocks = (npix + 3) / 4;                // 4 waves (pixels) / block
  roi_pool_kernel<<<blocks, 256, 0, stream>>>(img, rois, out, P, H, W, C, npix);
}